// Round 1
// baseline (127.521 us; speedup 1.0000x reference)
//
#include <hip/hip_runtime.h>

typedef float f32x4 __attribute__((ext_vector_type(4)));
typedef short bf16x8 __attribute__((ext_vector_type(8)));

constexpr int NB   = 16;
constexpr int LQ   = 2048;
constexpr int LK   = 2048;
constexpr int D    = 128;
constexpr int DV   = 128;
constexpr int QBLK = 64;
constexpr int KVBLK = 64;
constexpr float SCALE = 0.08838834764831843f;  // 1/sqrt(128)
constexpr float LOG2E = 1.4426950408889634f;

__device__ __forceinline__ unsigned short f2bf(float f) {
  unsigned int u = __float_as_uint(f);
  u += 0x7FFFu + ((u >> 16) & 1u);   // round-to-nearest-even
  return (unsigned short)(u >> 16);
}

// 16B-chunk XOR swizzle within a row (keeps ds_read_b128 conflict-free)
__device__ __forceinline__ int swzc(int row, int c16) {
  return c16 ^ ((row ^ (row >> 3)) & 7);
}

__global__ __launch_bounds__(256, 2) void attn_fwd(
    const float* __restrict__ qp, const float* __restrict__ kp,
    const float* __restrict__ vp, float* __restrict__ op) {
  // LDS layout (uint16 units):
  //   Q  [64][128]  @ 0      (16 KB)  row stride 128 elems, 16 chunks
  //   K  [64][128]  @ 8192   (16 KB)
  //   Vt [128][64]  @ 16384  (16 KB)  row stride 64 elems, 8 chunks
  //   P  4x[16][64] @ 24576  ( 8 KB)  per-wave private
  __shared__ __align__(16) unsigned short sm[28672];

  const int tid  = threadIdx.x;
  const int wid  = tid >> 6;
  const int lane = tid & 63;
  const int g    = lane >> 4;   // 16-lane group
  const int c    = lane & 15;
  const int b    = blockIdx.y;
  const int qb   = blockIdx.x * QBLK;

  const float* qg = qp + ((long)b * LQ + qb) * D;
  const float* kg = kp + (long)b * LK * D;
  const float* vg = vp + (long)b * LK * DV;

  // ---------------- stage Q once (scale folded in) ----------------
  #pragma unroll
  for (int it = 0; it < 4; ++it) {
    int ch  = it * 256 + tid;
    int row = ch >> 4, c16 = ch & 15;
    const float* src = qg + row * D + c16 * 8;
    f32x4 f0 = *(const f32x4*)(src);
    f32x4 f1 = *(const f32x4*)(src + 4);
    bf16x8 fr;
    #pragma unroll
    for (int j = 0; j < 4; ++j) {
      fr[j]     = (short)f2bf(f0[j] * SCALE);
      fr[4 + j] = (short)f2bf(f1[j] * SCALE);
    }
    *(bf16x8*)&sm[row * 128 + swzc(row, c16) * 8] = fr;
  }
  __syncthreads();

  // Q fragments persist in registers: A[m][k], m = lane&15, k-group = (lane>>4)*8
  bf16x8 aq[4];
  #pragma unroll
  for (int ks = 0; ks < 4; ++ks) {
    int row = wid * 16 + c;
    aq[ks] = *(const bf16x8*)&sm[row * 128 + swzc(row, ks * 4 + g) * 8];
  }

  f32x4 o[8];
  f32x4 fzero = {0.f, 0.f, 0.f, 0.f};
  #pragma unroll
  for (int i = 0; i < 8; ++i) o[i] = fzero;
  float m_r[4] = {-1e30f, -1e30f, -1e30f, -1e30f};
  float l_r[4] = {0.f, 0.f, 0.f, 0.f};

  const int pbase = 24576 + wid * 1024;

  for (int kv0 = 0; kv0 < LK; kv0 += KVBLK) {
    __syncthreads();   // all waves done reading previous K/V tiles

    // ---------------- stage K tile [64][128] ----------------
    const float* ksrc = kg + (long)kv0 * D;
    #pragma unroll
    for (int it = 0; it < 4; ++it) {
      int ch  = it * 256 + tid;
      int row = ch >> 4, c16 = ch & 15;
      const float* src = ksrc + row * D + c16 * 8;
      f32x4 f0 = *(const f32x4*)(src);
      f32x4 f1 = *(const f32x4*)(src + 4);
      bf16x8 fr;
      #pragma unroll
      for (int j = 0; j < 4; ++j) {
        fr[j]     = (short)f2bf(f0[j]);
        fr[4 + j] = (short)f2bf(f1[j]);
      }
      *(bf16x8*)&sm[8192 + row * 128 + swzc(row, c16) * 8] = fr;
    }

    // ---------------- stage V transposed -> Vt[128][64] ----------------
    {
      const float* vsrc = vg + (long)kv0 * DV;
      int dvq = (tid & 31) * 4;   // 4 dv columns per thread
      int kg8 = tid >> 5;         // 8-k group (0..7)
      f32x4 col[8];
      #pragma unroll
      for (int j = 0; j < 8; ++j)
        col[j] = *(const f32x4*)(vsrc + (kg8 * 8 + j) * DV + dvq);  // coalesced
      #pragma unroll
      for (int i = 0; i < 4; ++i) {
        int dv = dvq + i;
        bf16x8 fr;
        #pragma unroll
        for (int j = 0; j < 8; ++j) fr[j] = (short)f2bf(col[j][i]);
        *(bf16x8*)&sm[16384 + dv * 64 + swzc(dv, kg8) * 8] = fr;
      }
    }
    __syncthreads();

    // ---------------- S = (Q*scale) K^T : 4 col-tiles x 4 k-steps ----------------
    f32x4 s[4];
    #pragma unroll
    for (int t = 0; t < 4; ++t) s[t] = fzero;
    #pragma unroll
    for (int ks = 0; ks < 4; ++ks) {
      #pragma unroll
      for (int t = 0; t < 4; ++t) {
        int row = t * 16 + c;      // B[k][n]: n = k-row index of K tile
        bf16x8 bk = *(const bf16x8*)&sm[8192 + row * 128 + swzc(row, ks * 4 + g) * 8];
        s[t] = __builtin_amdgcn_mfma_f32_16x16x32_bf16(aq[ks], bk, s[t], 0, 0, 0);
      }
    }

    // ---------------- online softmax; lane owns rows g*4+r, cols c+16t ----------------
    #pragma unroll
    for (int r = 0; r < 4; ++r) {
      float pm = fmaxf(fmaxf(s[0][r], s[1][r]), fmaxf(s[2][r], s[3][r]));
      pm = fmaxf(pm, __shfl_xor(pm, 1));
      pm = fmaxf(pm, __shfl_xor(pm, 2));
      pm = fmaxf(pm, __shfl_xor(pm, 4));
      pm = fmaxf(pm, __shfl_xor(pm, 8));
      float mn = fmaxf(m_r[r], pm);
      float al = exp2f((m_r[r] - mn) * LOG2E);
      float sum = 0.f;
      #pragma unroll
      for (int t = 0; t < 4; ++t) {
        float p = exp2f((s[t][r] - mn) * LOG2E);
        s[t][r] = p;
        sum += p;
      }
      sum += __shfl_xor(sum, 1);
      sum += __shfl_xor(sum, 2);
      sum += __shfl_xor(sum, 4);
      sum += __shfl_xor(sum, 8);
      l_r[r] = l_r[r] * al + sum;
      m_r[r] = mn;
      #pragma unroll
      for (int dvt = 0; dvt < 8; ++dvt) o[dvt][r] *= al;
    }

    // ---------------- P (bf16) -> per-wave LDS region ----------------
    #pragma unroll
    for (int t = 0; t < 4; ++t) {
      #pragma unroll
      for (int r = 0; r < 4; ++r) {
        int row = g * 4 + r, colx = c + 16 * t;
        sm[pbase + row * 64 + swzc(row, colx >> 3) * 8 + (colx & 7)] = f2bf(s[t][r]);
      }
    }
    // (within-wave LDS RAW: compiler inserts lgkmcnt)

    // ---------------- O += P V ----------------
    #pragma unroll
    for (int ks = 0; ks < 2; ++ks) {
      bf16x8 pa = *(const bf16x8*)&sm[pbase + c * 64 + swzc(c, ks * 4 + g) * 8];
      #pragma unroll
      for (int dvt = 0; dvt < 8; ++dvt) {
        int row = dvt * 16 + c;   // Vt row = dv
        bf16x8 vb = *(const bf16x8*)&sm[16384 + row * 64 + swzc(row, ks * 4 + g) * 8];
        o[dvt] = __builtin_amdgcn_mfma_f32_16x16x32_bf16(pa, vb, o[dvt], 0, 0, 0);
      }
    }
  }

  // ---------------- epilogue: O / l ----------------
  float* dst = op + ((long)b * LQ + qb + wid * 16) * DV;
  #pragma unroll
  for (int r = 0; r < 4; ++r) {
    float inv = 1.f / l_r[r];
    #pragma unroll
    for (int dvt = 0; dvt < 8; ++dvt)
      dst[(g * 4 + r) * DV + dvt * 16 + c] = o[dvt][r] * inv;
  }
}

extern "C" void kernel_launch(void* const* d_in, const int* in_sizes, int n_in,
                              void* d_out, int out_size, void* d_ws, size_t ws_size,
                              hipStream_t stream) {
  const float* q = (const float*)d_in[0];
  const float* k = (const float*)d_in[1];
  const float* v = (const float*)d_in[2];
  float* out = (float*)d_out;
  dim3 grid(LQ / QBLK, NB);
  attn_fwd<<<grid, dim3(256), 0, stream>>>(q, k, v, out);
}

// Round 2
// 80.647 us; speedup vs baseline: 1.5812x; 1.5812x over previous
//
#include <hip/hip_runtime.h>
#include <hip/hip_bf16.h>

typedef float f32x4 __attribute__((ext_vector_type(4)));
typedef short bf16x8 __attribute__((ext_vector_type(8)));

constexpr int NB = 16, LQ = 2048, LK = 2048, D = 128, DV = 128;
constexpr int QBLK = 64, KVBLK = 64, NT = LK / KVBLK;
constexpr float SCALE = 0.08838834764831843f;   // 1/sqrt(128)
constexpr float LOG2E = 1.4426950408889634f;
constexpr float QSCALE = SCALE * LOG2E;         // softmax in log2 domain

// ---------- helpers ----------
__device__ __forceinline__ unsigned short f2bfs(float f) {
  __hip_bfloat16 h = __float2bfloat16(f);      // RNE; compiler fuses pairs to v_cvt_pk_bf16_f32
  return __builtin_bit_cast(unsigned short, h);
}

// legacy manual RNE convert (used by fallback kernel)
__device__ __forceinline__ unsigned short f2bf(float f) {
  unsigned int u = __float_as_uint(f);
  u += 0x7FFFu + ((u >> 16) & 1u);
  return (unsigned short)(u >> 16);
}

// 3-bit XOR chunk swizzle with full row entropy for our read patterns
__device__ __forceinline__ int swz2(int row) {
  return (row ^ (row >> 1) ^ (row >> 3)) & 7;
}

typedef const __attribute__((address_space(1))) void* gas1_t;
typedef __attribute__((address_space(3))) void* las3_t;
__device__ __forceinline__ void gload16(const void* g, void* l) {
  __builtin_amdgcn_global_load_lds((gas1_t)g, (las3_t)l, 16, 0, 0);
}

// ---------- prepass: fp32 -> bf16 (optionally scaled) ----------
__global__ __launch_bounds__(256) void conv_bf16(const float* __restrict__ in,
                                                 unsigned short* __restrict__ out,
                                                 float scale) {
  int i = blockIdx.x * 256 + threadIdx.x;       // 8 elems / thread
  f32x4 a = ((const f32x4*)in)[2 * i];
  f32x4 b = ((const f32x4*)in)[2 * i + 1];
  bf16x8 r;
  #pragma unroll
  for (int j = 0; j < 4; ++j) {
    r[j]     = (short)f2bfs(a[j] * scale);
    r[4 + j] = (short)f2bfs(b[j] * scale);
  }
  ((bf16x8*)out)[i] = r;
}

// ---------- prepass: V[b][k][dv] fp32 -> Vt[b][dv][k] bf16 ----------
__global__ __launch_bounds__(256) void conv_vt(const float* __restrict__ v,
                                               unsigned short* __restrict__ vt) {
  __shared__ __align__(16) unsigned short tb[64 * 64];
  const int tid = threadIdx.x;
  const int k0 = blockIdx.x * 64, dv0 = blockIdx.y * 64, b = blockIdx.z;
  {
    const int kk = tid >> 2, dd0 = (tid & 3) * 16;
    const float* src = v + ((long)(b * LK + k0 + kk)) * DV + dv0 + dd0;
    f32x4 a0 = ((const f32x4*)src)[0];
    f32x4 a1 = ((const f32x4*)src)[1];
    f32x4 a2 = ((const f32x4*)src)[2];
    f32x4 a3 = ((const f32x4*)src)[3];
    bf16x8 r0, r1;
    #pragma unroll
    for (int j = 0; j < 4; ++j) {
      r0[j] = (short)f2bfs(a0[j]); r0[4 + j] = (short)f2bfs(a1[j]);
      r1[j] = (short)f2bfs(a2[j]); r1[4 + j] = (short)f2bfs(a3[j]);
    }
    int ch = dd0 >> 3;
    *(bf16x8*)&tb[kk * 64 + ((ch ^ swz2(kk)) << 3)] = r0;
    *(bf16x8*)&tb[kk * 64 + (((ch + 1) ^ swz2(kk)) << 3)] = r1;
  }
  __syncthreads();
  {
    const int dv = tid >> 2, ks = (tid & 3) * 16;
    bf16x8 w0, w1;
    #pragma unroll
    for (int j = 0; j < 8; ++j) {
      int r0 = ks + j, r1 = ks + 8 + j;
      w0[j] = (short)tb[r0 * 64 + (((dv >> 3) ^ swz2(r0)) << 3) + (dv & 7)];
      w1[j] = (short)tb[r1 * 64 + (((dv >> 3) ^ swz2(r1)) << 3) + (dv & 7)];
    }
    unsigned short* dst = vt + ((long)(b * DV + dv0 + dv)) * LK + k0 + ks;
    *(bf16x8*)dst = w0;
    *(bf16x8*)(dst + 8) = w1;
  }
}

// ---------- main: flash attention, bf16 MFMA, P-in-register ----------
__global__ __launch_bounds__(256, 2) void attn_fwd2(
    const float* __restrict__ qp, const unsigned short* __restrict__ wsK,
    const unsigned short* __restrict__ wsVt, float* __restrict__ op) {
  // LDS: 2 x (K[64][128] + Vt[128][64]) bf16 = 64 KB, 16B-chunk swizzled
  __shared__ __align__(16) unsigned short sm[32768];

  const int tid = threadIdx.x;
  const int wid = tid >> 6;
  const int lane = tid & 63;
  const int g = lane >> 4;
  const int c = lane & 15;

  // XCD-aware block swizzle: 64 consecutive blocks (2 batches) per XCD
  const int bid = blockIdx.x;                 // 512 blocks
  const int sbid = (bid & 7) * 64 + (bid >> 3);
  const int b = sbid >> 5;
  const int qb = (sbid & 31) * QBLK;

  // Q fragments (B-operand): Q[q=c][d], converted once, scale*log2e folded
  const float* qrow = qp + ((long)(b * LQ + qb + wid * 16 + c)) * D;
  bf16x8 aq[4];
  #pragma unroll
  for (int ks = 0; ks < 4; ++ks) {
    f32x4 x0 = *(const f32x4*)(qrow + ks * 32 + g * 8);
    f32x4 x1 = *(const f32x4*)(qrow + ks * 32 + g * 8 + 4);
    #pragma unroll
    for (int j = 0; j < 4; ++j) {
      aq[ks][j]     = (short)f2bfs(x0[j] * QSCALE);
      aq[ks][4 + j] = (short)f2bfs(x1[j] * QSCALE);
    }
  }

  const unsigned short* kbatch = wsK + (long)b * LK * D;
  const unsigned short* vbatch = wsVt + (long)b * DV * LK;

  // stage one KV tile into buffer `buf` (linear LDS dest, inverse-swizzled src)
  auto stage = [&](int buf, int kv0) {
    const unsigned short* ksrc = kbatch + (long)kv0 * D;
    #pragma unroll
    for (int it = 0; it < 4; ++it) {
      int ci = it * 256 + tid, row = ci >> 4, c16 = ci & 15;
      gload16(ksrc + row * D + ((c16 ^ swz2(row)) << 3), &sm[buf * 16384 + ci * 8]);
    }
    #pragma unroll
    for (int it = 0; it < 4; ++it) {
      int ci = it * 256 + tid, row = ci >> 3, c8 = ci & 7;
      gload16(vbatch + (long)row * LK + kv0 + ((c8 ^ swz2(row)) << 3),
              &sm[buf * 16384 + 8192 + ci * 8]);
    }
  };

  stage(0, 0);
  __syncthreads();   // compiler drains vmcnt(0) before s_barrier

  f32x4 o[8];
  f32x4 fz = {0.f, 0.f, 0.f, 0.f};
  #pragma unroll
  for (int i = 0; i < 8; ++i) o[i] = fz;
  float m_s = -1e30f, l_s = 0.f;

  for (int t = 0; t < NT; ++t) {
    const int cur = t & 1;
    if (t + 1 < NT) stage(cur ^ 1, (t + 1) * KVBLK);
    const int kb = cur * 16384, vb = kb + 8192;

    // ---- S^T = K Q^T with k-row permutation F(t,m)=(m&3)+32(t>>1)+8(m>>2)+4(t&1)
    // lane (g,c) ends up holding P[q=c][k=32*(tt>>1)+4*(tt&1)+8g+r] in s[tt][r]
    f32x4 s[4];
    #pragma unroll
    for (int i = 0; i < 4; ++i) s[i] = fz;
    __builtin_amdgcn_s_setprio(1);
    #pragma unroll
    for (int tt = 0; tt < 4; ++tt) {
      int row = 32 * (tt >> 1) + 4 * (tt & 1) + (c & 3) + ((c >> 2) << 3);
      int sz = swz2(row);
      #pragma unroll
      for (int ks = 0; ks < 4; ++ks) {
        bf16x8 ak = *(const bf16x8*)&sm[kb + row * 128 + ((((ks << 2) + g) ^ sz) << 3)];
        s[tt] = __builtin_amdgcn_mfma_f32_16x16x32_bf16(ak, aq[ks], s[tt], 0, 0, 0);
      }
    }
    __builtin_amdgcn_s_setprio(0);

    // ---- online softmax (log2 domain), lane owns q=c over all 16 k-values
    float pm = s[0][0];
    #pragma unroll
    for (int tt = 0; tt < 4; ++tt)
      #pragma unroll
      for (int r = 0; r < 4; ++r) pm = fmaxf(pm, s[tt][r]);
    pm = fmaxf(pm, __shfl_xor(pm, 16));
    pm = fmaxf(pm, __shfl_xor(pm, 32));
    if (!__all(pm <= m_s + 8.0f)) {            // defer-max (T13)
      float mn = fmaxf(m_s, pm);
      float al = exp2f(m_s - mn);
      l_s *= al;
      float al4[4];
      #pragma unroll
      for (int r = 0; r < 4; ++r) al4[r] = __shfl(al, 4 * g + r);
      #pragma unroll
      for (int dvt = 0; dvt < 8; ++dvt)
        #pragma unroll
        for (int r = 0; r < 4; ++r) o[dvt][r] *= al4[r];
      m_s = mn;
    }
    float sum = 0.f;
    #pragma unroll
    for (int tt = 0; tt < 4; ++tt)
      #pragma unroll
      for (int r = 0; r < 4; ++r) {
        float p = exp2f(s[tt][r] - m_s);
        s[tt][r] = p;
        sum += p;
      }
    sum += __shfl_xor(sum, 16);
    sum += __shfl_xor(sum, 32);
    l_s += sum;

    // ---- P is already lane-local in A-fragment layout: just pack to bf16
    bf16x8 pa[2];
    #pragma unroll
    for (int ks = 0; ks < 2; ++ks) {
      #pragma unroll
      for (int j = 0; j < 4; ++j) {
        pa[ks][j]     = (short)f2bfs(s[2 * ks][j]);
        pa[ks][4 + j] = (short)f2bfs(s[2 * ks + 1][j]);
      }
    }

    // ---- O += P V
    __builtin_amdgcn_s_setprio(1);
    #pragma unroll
    for (int ks = 0; ks < 2; ++ks) {
      #pragma unroll
      for (int dvt = 0; dvt < 8; ++dvt) {
        int row = dvt * 16 + c;
        bf16x8 vbf = *(const bf16x8*)&sm[vb + row * 64 + ((((ks << 2) + g) ^ swz2(row)) << 3)];
        o[dvt] = __builtin_amdgcn_mfma_f32_16x16x32_bf16(pa[ks], vbf, o[dvt], 0, 0, 0);
      }
    }
    __builtin_amdgcn_s_setprio(0);

    __syncthreads();   // drains staged loads (vmcnt 0) + all reads of cur done
  }

  // ---- epilogue: O / l  (o[dvt][r] is O[q=4g+r][dv=16dvt+c])
  float linv[4];
  #pragma unroll
  for (int r = 0; r < 4; ++r) linv[r] = 1.f / __shfl(l_s, 4 * g + r);
  float* dst = op + ((long)(b * LQ + qb + wid * 16)) * DV;
  #pragma unroll
  for (int r = 0; r < 4; ++r)
    #pragma unroll
    for (int dvt = 0; dvt < 8; ++dvt)
      dst[(4 * g + r) * DV + dvt * 16 + c] = o[dvt][r] * linv[r];
}

// ---------- legacy fallback (round-1 kernel, used if ws too small) ----------
__device__ __forceinline__ int swzc(int row, int c16) {
  return c16 ^ ((row ^ (row >> 3)) & 7);
}

__global__ __launch_bounds__(256, 2) void attn_fwd(
    const float* __restrict__ qp, const float* __restrict__ kp,
    const float* __restrict__ vp, float* __restrict__ op) {
  __shared__ __align__(16) unsigned short smm[28672];
  const int tid = threadIdx.x, wid = tid >> 6, lane = tid & 63;
  const int g = lane >> 4, c = lane & 15;
  const int b = blockIdx.y, qb = blockIdx.x * QBLK;
  const float* qg = qp + ((long)b * LQ + qb) * D;
  const float* kg = kp + (long)b * LK * D;
  const float* vg = vp + (long)b * LK * DV;
  #pragma unroll
  for (int it = 0; it < 4; ++it) {
    int ch = it * 256 + tid, row = ch >> 4, c16 = ch & 15;
    const float* src = qg + row * D + c16 * 8;
    f32x4 f0 = *(const f32x4*)(src);
    f32x4 f1 = *(const f32x4*)(src + 4);
    bf16x8 fr;
    #pragma unroll
    for (int j = 0; j < 4; ++j) {
      fr[j] = (short)f2bf(f0[j] * SCALE);
      fr[4 + j] = (short)f2bf(f1[j] * SCALE);
    }
    *(bf16x8*)&smm[row * 128 + swzc(row, c16) * 8] = fr;
  }
  __syncthreads();
  bf16x8 aq[4];
  #pragma unroll
  for (int ks = 0; ks < 4; ++ks) {
    int row = wid * 16 + c;
    aq[ks] = *(const bf16x8*)&smm[row * 128 + swzc(row, ks * 4 + g) * 8];
  }
  f32x4 o[8]; f32x4 fz = {0.f, 0.f, 0.f, 0.f};
  #pragma unroll
  for (int i = 0; i < 8; ++i) o[i] = fz;
  float m_r[4] = {-1e30f, -1e30f, -1e30f, -1e30f};
  float l_r[4] = {0.f, 0.f, 0.f, 0.f};
  const int pbase = 24576 + wid * 1024;
  for (int kv0 = 0; kv0 < LK; kv0 += KVBLK) {
    __syncthreads();
    const float* ksrc = kg + (long)kv0 * D;
    #pragma unroll
    for (int it = 0; it < 4; ++it) {
      int ch = it * 256 + tid, row = ch >> 4, c16 = ch & 15;
      const float* src = ksrc + row * D + c16 * 8;
      f32x4 f0 = *(const f32x4*)(src);
      f32x4 f1 = *(const f32x4*)(src + 4);
      bf16x8 fr;
      #pragma unroll
      for (int j = 0; j < 4; ++j) { fr[j] = (short)f2bf(f0[j]); fr[4 + j] = (short)f2bf(f1[j]); }
      *(bf16x8*)&smm[8192 + row * 128 + swzc(row, c16) * 8] = fr;
    }
    {
      const float* vsrc = vg + (long)kv0 * DV;
      int dvq = (tid & 31) * 4, kg8 = tid >> 5;
      f32x4 col[8];
      #pragma unroll
      for (int j = 0; j < 8; ++j) col[j] = *(const f32x4*)(vsrc + (kg8 * 8 + j) * DV + dvq);
      #pragma unroll
      for (int i = 0; i < 4; ++i) {
        int dv = dvq + i;
        bf16x8 fr;
        #pragma unroll
        for (int j = 0; j < 8; ++j) fr[j] = (short)f2bf(col[j][i]);
        *(bf16x8*)&smm[16384 + dv * 64 + swzc(dv, kg8) * 8] = fr;
      }
    }
    __syncthreads();
    f32x4 s[4];
    #pragma unroll
    for (int i = 0; i < 4; ++i) s[i] = fz;
    #pragma unroll
    for (int ks = 0; ks < 4; ++ks) {
      #pragma unroll
      for (int t = 0; t < 4; ++t) {
        int row = t * 16 + c;
        bf16x8 bk = *(const bf16x8*)&smm[8192 + row * 128 + swzc(row, ks * 4 + g) * 8];
        s[t] = __builtin_amdgcn_mfma_f32_16x16x32_bf16(aq[ks], bk, s[t], 0, 0, 0);
      }
    }
    #pragma unroll
    for (int r = 0; r < 4; ++r) {
      float pm = fmaxf(fmaxf(s[0][r], s[1][r]), fmaxf(s[2][r], s[3][r]));
      pm = fmaxf(pm, __shfl_xor(pm, 1));
      pm = fmaxf(pm, __shfl_xor(pm, 2));
      pm = fmaxf(pm, __shfl_xor(pm, 4));
      pm = fmaxf(pm, __shfl_xor(pm, 8));
      float mn = fmaxf(m_r[r], pm);
      float al = exp2f((m_r[r] - mn) * LOG2E);
      float sum = 0.f;
      #pragma unroll
      for (int t = 0; t < 4; ++t) {
        float p = exp2f((s[t][r] - mn) * LOG2E);
        s[t][r] = p; sum += p;
      }
      sum += __shfl_xor(sum, 1); sum += __shfl_xor(sum, 2);
      sum += __shfl_xor(sum, 4); sum += __shfl_xor(sum, 8);
      l_r[r] = l_r[r] * al + sum; m_r[r] = mn;
      #pragma unroll
      for (int dvt = 0; dvt < 8; ++dvt) o[dvt][r] *= al;
    }
    #pragma unroll
    for (int t = 0; t < 4; ++t)
      #pragma unroll
      for (int r = 0; r < 4; ++r) {
        int row = g * 4 + r, colx = c + 16 * t;
        smm[pbase + row * 64 + swzc(row, colx >> 3) * 8 + (colx & 7)] = f2bf(s[t][r]);
      }
    #pragma unroll
    for (int ks = 0; ks < 2; ++ks) {
      bf16x8 pa = *(const bf16x8*)&smm[pbase + c * 64 + swzc(c, ks * 4 + g) * 8];
      #pragma unroll
      for (int dvt = 0; dvt < 8; ++dvt) {
        int row = dvt * 16 + c;
        bf16x8 vb2 = *(const bf16x8*)&smm[16384 + row * 64 + swzc(row, ks * 4 + g) * 8];
        o[dvt] = __builtin_amdgcn_mfma_f32_16x16x32_bf16(pa, vb2, o[dvt], 0, 0, 0);
      }
    }
  }
  float* dst = op + ((long)b * LQ + qb + wid * 16) * DV;
  #pragma unroll
  for (int r = 0; r < 4; ++r) {
    float inv = 1.f / l_r[r];
    #pragma unroll
    for (int dvt = 0; dvt < 8; ++dvt)
      dst[(g * 4 + r) * DV + dvt * 16 + c] = o[dvt][r] * inv;
  }
}

extern "C" void kernel_launch(void* const* d_in, const int* in_sizes, int n_in,
                              void* d_out, int out_size, void* d_ws, size_t ws_size,
                              hipStream_t stream) {
  const float* q = (const float*)d_in[0];
  const float* k = (const float*)d_in[1];
  const float* v = (const float*)d_in[2];
  float* out = (float*)d_out;

  const size_t kelems = (size_t)NB * LK * D;          // 4.19M
  const size_t need = kelems * 2 * 2;                 // K + Vt, bf16
  if (ws_size >= need) {
    unsigned short* wsK = (unsigned short*)d_ws;
    unsigned short* wsVt = wsK + kelems;
    conv_bf16<<<dim3((int)(kelems / 8 / 256)), dim3(256), 0, stream>>>(k, wsK, 1.0f);
    conv_vt<<<dim3(LK / 64, DV / 64, NB), dim3(256), 0, stream>>>(v, wsVt);
    attn_fwd2<<<dim3(NB * LQ / QBLK), dim3(256), 0, stream>>>(q, wsK, wsVt, out);
  } else {
    attn_fwd<<<dim3(LQ / QBLK, NB), dim3(256), 0, stream>>>(q, k, v, out);
  }
}